// Round 1
// baseline (1766.565 us; speedup 1.0000x reference)
//
#include <hip/hip_runtime.h>
#include <stddef.h>

#define NPTS 16384
#define NB   16
#define NS   512
#define NK   32
#define CNTF 262144.0f

// workspace layout (bytes)
static constexpr size_t O_FPS  = 0;          // int[16*512]
static constexpr size_t O_NXYZ = 32768;      // float[16*512*3]
static constexpr size_t O_IDX  = 131072;     // int[16*512*32]
static constexpr size_t O_SC   = 1179648;    // float[512]: s1,h1,s2,h2,s3(128),h3(128)
static constexpr size_t O_P1   = 1181696;    // float[1024*128]
static constexpr size_t O_P2   = 1705984;    // float[2048*128]
static constexpr size_t O_P3   = 2754560;    // float[2048*256]
static constexpr size_t O_MX   = 4851712;    // float[16*512*128]
static constexpr size_t O_MN   = 9046016;    // float[16*512*128]
static constexpr size_t O_Y1   = 13240320;   // float[262144*64]
static constexpr size_t O_Y2   = 80349184;   // float[262144*64]

// ---------------- FPS: one block per batch, points in registers ----------------
__global__ __launch_bounds__(1024) void fps_kernel(const float* __restrict__ xyz,
    int* __restrict__ fps_idx, float* __restrict__ out_nx, float* __restrict__ nxyz_c)
{
    const int b = blockIdx.x;
    const int t = threadIdx.x;
    const float* xb = xyz + (size_t)b * (3 * NPTS);
    float px[16], py[16], pz[16], dist[16];
#pragma unroll
    for (int i = 0; i < 16; ++i) {
        int p = i * 1024 + t;
        px[i] = xb[p]; py[i] = xb[NPTS + p]; pz[i] = xb[2 * NPTS + p];
        dist[i] = 1e10f;
    }
    __shared__ float red_v[16];
    __shared__ int   red_i[16];
    __shared__ int   s_far;
    int far = 0;
    for (int it = 0; it < NS; ++it) {
        float cx = xb[far], cy = xb[NPTS + far], cz = xb[2 * NPTS + far];
        if (t == 0) {
            fps_idx[b * NS + it] = far;
            out_nx[(b * 3 + 0) * NS + it] = cx;
            out_nx[(b * 3 + 1) * NS + it] = cy;
            out_nx[(b * 3 + 2) * NS + it] = cz;
            float* nc = nxyz_c + ((size_t)(b * NS + it)) * 3;
            nc[0] = cx; nc[1] = cy; nc[2] = cz;
        }
        float bestv = -1.0f; int besti = 0x7fffffff;
#pragma unroll
        for (int i = 0; i < 16; ++i) {
            float dx = px[i] - cx, dy = py[i] - cy, dz = pz[i] - cz;
            float d = dx * dx + dy * dy + dz * dz;
            float nd = fminf(dist[i], d);
            dist[i] = nd;
            bool better = (nd > bestv);
            bestv = better ? nd : bestv;
            besti = better ? (i * 1024 + t) : besti;
        }
#pragma unroll
        for (int off = 32; off >= 1; off >>= 1) {
            float ov = __shfl_xor(bestv, off);
            int   oi = __shfl_xor(besti, off);
            bool take = (ov > bestv) || (ov == bestv && oi < besti);
            bestv = take ? ov : bestv;
            besti = take ? oi : besti;
        }
        int w = t >> 6;
        if ((t & 63) == 0) { red_v[w] = bestv; red_i[w] = besti; }
        __syncthreads();
        if (t < 64) {
            float v = (t < 16) ? red_v[t] : -1.0f;
            int   i = (t < 16) ? red_i[t] : 0x7fffffff;
#pragma unroll
            for (int off = 8; off >= 1; off >>= 1) {
                float ov = __shfl_xor(v, off);
                int   oi = __shfl_xor(i, off);
                bool take = (ov > v) || (ov == v && oi < i);
                v = take ? ov : v;
                i = take ? oi : i;
            }
            if (t == 0) s_far = i;
        }
        __syncthreads();
        far = __builtin_amdgcn_readfirstlane(s_far);
    }
}

// ---------------- Ball query: one wave per (b,s), first-32-hits scan ----------------
__global__ __launch_bounds__(256) void ballq_kernel(const float* __restrict__ xyz,
    const float* __restrict__ nxyz_c, int* __restrict__ idx)
{
    const int gw = (blockIdx.x * 256 + threadIdx.x) >> 6;
    const int lane = threadIdx.x & 63;
    const int b = gw >> 9;
    const float* xb = xyz + (size_t)b * (3 * NPTS);
    const float* a = nxyz_c + (size_t)gw * 3;
    const float ax = a[0], ay = a[1], az = a[2];
    const float aa = ax * ax + ay * ay + az * az;
    const unsigned long long lmask = (lane == 63) ? 0x7fffffffffffffffull
                                                  : ((1ull << lane) - 1ull);
    int cnt = 0, first = -1;
    int* op = idx + (size_t)gw * NK;
    for (int base = 0; base < NPTS; base += 64) {
        int p = base + lane;
        float bx = xb[p], by = xb[NPTS + p], bz = xb[2 * NPTS + p];
        float bb = bx * bx + by * by + bz * bz;
        float ab = ax * bx + ay * by + az * bz;
        float sq = (aa - 2.0f * ab) + bb;
        bool hit = !(sq > 0.04f);
        unsigned long long m = __ballot(hit);
        if (m) {
            if (first < 0) first = base + (__ffsll((unsigned long long)m) - 1);
            if (hit) {
                int slot = cnt + __popcll(m & lmask);
                if (slot < NK) op[slot] = p;
            }
            cnt += __popcll(m);
            if (cnt >= NK) break;
        }
    }
    if (cnt < NK && lane >= cnt && lane < NK) op[lane] = first;
}

// ---------------- Conv1 (9->64) + stats partials ----------------
__global__ __launch_bounds__(256) void conv1_kernel(const float* __restrict__ xyz,
    const float* __restrict__ points, const float* __restrict__ nxyz_c,
    const int* __restrict__ idx, const float* __restrict__ W0, const float* __restrict__ b0,
    float* __restrict__ y1, float* __restrict__ part)
{
    const int lane = threadIdx.x & 63;
    const int w = threadIdx.x >> 6;
    const int wid = blockIdx.x * 4 + w;
    float wr[9];
#pragma unroll
    for (int c = 0; c < 9; ++c) wr[c] = W0[lane * 9 + c];
    const float bias = b0[lane];
    float sum = 0.f, sq = 0.f;
    const int r0 = wid * 64;
    for (int rr = 0; rr < 64; ++rr) {
        int r = r0 + rr;
        int b = r >> 14;
        int s = (r >> 5) & 511;
        int pidx = idx[r];
        const float* xb = xyz + (size_t)b * (3 * NPTS);
        const float* pb = points + (size_t)b * (6 * NPTS);
        const float* nc = nxyz_c + ((size_t)(b * NS + s)) * 3;
        float f0 = xb[pidx] - nc[0];
        float f1 = xb[NPTS + pidx] - nc[1];
        float f2 = xb[2 * NPTS + pidx] - nc[2];
        float f3 = pb[pidx];
        float f4 = pb[NPTS + pidx];
        float f5 = pb[2 * NPTS + pidx];
        float f6 = pb[3 * NPTS + pidx];
        float f7 = pb[4 * NPTS + pidx];
        float f8 = pb[5 * NPTS + pidx];
        float acc = bias;
        acc = fmaf(wr[0], f0, acc); acc = fmaf(wr[1], f1, acc); acc = fmaf(wr[2], f2, acc);
        acc = fmaf(wr[3], f3, acc); acc = fmaf(wr[4], f4, acc); acc = fmaf(wr[5], f5, acc);
        acc = fmaf(wr[6], f6, acc); acc = fmaf(wr[7], f7, acc); acc = fmaf(wr[8], f8, acc);
        y1[(size_t)r * 64 + lane] = acc;
        sum += acc; sq = fmaf(acc, acc, sq);
    }
    __shared__ float sred[4 * 128];
    sred[w * 128 + lane] = sum;
    sred[w * 128 + 64 + lane] = sq;
    __syncthreads();
    if (threadIdx.x < 128) {
        float tot = sred[threadIdx.x] + sred[128 + threadIdx.x]
                  + sred[256 + threadIdx.x] + sred[384 + threadIdx.x];
        part[(size_t)blockIdx.x * 128 + threadIdx.x] = tot;
    }
}

// ---------------- Conv2 (64->64) + stats partials ----------------
__global__ __launch_bounds__(256) void conv2_kernel(const float* __restrict__ y1,
    const float* __restrict__ W1, const float* __restrict__ b1,
    const float* __restrict__ scales, float* __restrict__ y2, float* __restrict__ part)
{
    const int lane = threadIdx.x & 63;
    const int w = threadIdx.x >> 6;
    const int wid = blockIdx.x * 4 + w;
    float wr[64];
#pragma unroll
    for (int c = 0; c < 64; ++c) wr[c] = W1[lane * 64 + c];
    const float bias = b1[lane];
    const float sc = scales[lane];
    const float sh = scales[64 + lane];
    float sum = 0.f, sq = 0.f;
    const int r0 = wid * 32;
    for (int rr = 0; rr < 32; ++rr) {
        int r = r0 + rr;
        float v = y1[(size_t)r * 64 + lane];
        float a = fmaxf(fmaf(sc, v, sh), 0.f);
        float acc = bias;
#pragma unroll
        for (int c = 0; c < 64; ++c) acc = fmaf(wr[c], __shfl(a, c), acc);
        y2[(size_t)r * 64 + lane] = acc;
        sum += acc; sq = fmaf(acc, acc, sq);
    }
    __shared__ float sred[4 * 128];
    sred[w * 128 + lane] = sum;
    sred[w * 128 + 64 + lane] = sq;
    __syncthreads();
    if (threadIdx.x < 128) {
        float tot = sred[threadIdx.x] + sred[128 + threadIdx.x]
                  + sred[256 + threadIdx.x] + sred[384 + threadIdx.x];
        part[(size_t)blockIdx.x * 128 + threadIdx.x] = tot;
    }
}

// ---------------- Conv3 (64->128) + stats partials + max/min over K ----------------
__global__ __launch_bounds__(256) void conv3_kernel(const float* __restrict__ y2,
    const float* __restrict__ W2, const float* __restrict__ b2,
    const float* __restrict__ scales, float* __restrict__ mx, float* __restrict__ mn,
    float* __restrict__ part)
{
    __shared__ float w2b[64 * 64];   // [c][o] for out channels 64..127
    __shared__ float sred[4 * 256];
    for (int j = threadIdx.x; j < 4096; j += 256) {
        int c = j >> 6, o = j & 63;
        w2b[j] = W2[(size_t)(64 + o) * 64 + c];
    }
    __syncthreads();
    const int lane = threadIdx.x & 63;
    const int w = threadIdx.x >> 6;
    const int wid = blockIdx.x * 4 + w;   // = b*512+s
    float wrA[64];
#pragma unroll
    for (int c = 0; c < 64; ++c) wrA[c] = W2[lane * 64 + c];
    const float biasA = b2[lane], biasB = b2[64 + lane];
    const float sc = scales[128 + lane], sh = scales[192 + lane];
    float sA = 0.f, sqA = 0.f, sB = 0.f, sqB = 0.f;
    float mxA = -3.4e38f, mnA = 3.4e38f, mxB = -3.4e38f, mnB = 3.4e38f;
    const int r0 = wid * 32;
    for (int k = 0; k < NK; ++k) {
        int r = r0 + k;
        float v = y2[(size_t)r * 64 + lane];
        float a = fmaxf(fmaf(sc, v, sh), 0.f);
        float accA = biasA, accB = biasB;
#pragma unroll
        for (int c = 0; c < 64; ++c) {
            float av = __shfl(a, c);
            accA = fmaf(wrA[c], av, accA);
            accB = fmaf(w2b[c * 64 + lane], av, accB);
        }
        sA += accA; sqA = fmaf(accA, accA, sqA);
        sB += accB; sqB = fmaf(accB, accB, sqB);
        mxA = fmaxf(mxA, accA); mnA = fminf(mnA, accA);
        mxB = fmaxf(mxB, accB); mnB = fminf(mnB, accB);
    }
    mx[(size_t)wid * 128 + lane] = mxA;
    mx[(size_t)wid * 128 + 64 + lane] = mxB;
    mn[(size_t)wid * 128 + lane] = mnA;
    mn[(size_t)wid * 128 + 64 + lane] = mnB;
    sred[w * 256 + lane] = sA;
    sred[w * 256 + 64 + lane] = sB;
    sred[w * 256 + 128 + lane] = sqA;
    sred[w * 256 + 192 + lane] = sqB;
    __syncthreads();
    {
        int t = threadIdx.x;
        float tot = sred[t] + sred[256 + t] + sred[512 + t] + sred[768 + t];
        part[(size_t)blockIdx.x * 256 + t] = tot;
    }
}

// ---------------- BN stats -> per-channel scale/shift ----------------
__global__ __launch_bounds__(1024) void stats_kernel(const float* __restrict__ part,
    int nparts, int nch, const float* __restrict__ g, const float* __restrict__ be,
    float* __restrict__ scale, float* __restrict__ shift)
{
    __shared__ float s_s[1024], s_q[1024];
    const int t = threadIdx.x;
    const int groups = 1024 / nch;
    const int gid = t / nch;
    const int o = t % nch;
    const int chunk = nparts / groups;
    float sum = 0.f, sq = 0.f;
    for (int p = gid * chunk; p < (gid + 1) * chunk; ++p) {
        sum += part[(size_t)p * 2 * nch + o];
        sq  += part[(size_t)p * 2 * nch + nch + o];
    }
    s_s[t] = sum; s_q[t] = sq;
    __syncthreads();
    if (t < nch) {
        float S = 0.f, Q = 0.f;
        for (int gi = 0; gi < groups; ++gi) { S += s_s[gi * nch + o]; Q += s_q[gi * nch + o]; }
        float m = S / CNTF;
        float v = Q / CNTF - m * m;
        v = v < 0.f ? 0.f : v;
        float scv = g[o] / sqrtf(v + 1e-5f);
        scale[o] = scv;
        shift[o] = be[o] - m * scv;
    }
}

// ---------------- Final: BN3+ReLU+max over K via (mx,mn) ----------------
__global__ __launch_bounds__(256) void final_kernel(const float* __restrict__ mx,
    const float* __restrict__ mn, const float* __restrict__ scales, float* __restrict__ out)
{
    int tid = blockIdx.x * 256 + threadIdx.x;   // b*65536 + o*512 + s
    int b = tid >> 16;
    int o = (tid >> 9) & 127;
    int s = tid & 511;
    int row = (b * NS + s) * 128 + o;
    float sc = scales[256 + o], sh = scales[384 + o];
    float vmx = mx[row], vmn = mn[row];
    float y = fmaxf(fmaf(sc, vmx, sh), fmaf(sc, vmn, sh));
    out[tid] = fmaxf(y, 0.f);
}

extern "C" void kernel_launch(void* const* d_in, const int* in_sizes, int n_in,
                              void* d_out, int out_size, void* d_ws, size_t ws_size,
                              hipStream_t stream)
{
    (void)in_sizes; (void)n_in; (void)out_size; (void)ws_size;
    const float* xyz    = (const float*)d_in[0];
    const float* points = (const float*)d_in[1];
    const float* W0  = (const float*)d_in[2];
    const float* b0  = (const float*)d_in[3];
    const float* g0  = (const float*)d_in[4];
    const float* be0 = (const float*)d_in[5];
    const float* W1  = (const float*)d_in[6];
    const float* b1  = (const float*)d_in[7];
    const float* g1  = (const float*)d_in[8];
    const float* be1 = (const float*)d_in[9];
    const float* W2  = (const float*)d_in[10];
    const float* b2  = (const float*)d_in[11];
    const float* g2  = (const float*)d_in[12];
    const float* be2 = (const float*)d_in[13];

    char* ws = (char*)d_ws;
    int*   fps  = (int*)(ws + O_FPS);
    float* nxyz = (float*)(ws + O_NXYZ);
    int*   idx  = (int*)(ws + O_IDX);
    float* scl  = (float*)(ws + O_SC);
    float* p1   = (float*)(ws + O_P1);
    float* p2   = (float*)(ws + O_P2);
    float* p3   = (float*)(ws + O_P3);
    float* mx   = (float*)(ws + O_MX);
    float* mn   = (float*)(ws + O_MN);
    float* y1   = (float*)(ws + O_Y1);
    float* y2   = (float*)(ws + O_Y2);
    float* out  = (float*)d_out;

    fps_kernel<<<16, 1024, 0, stream>>>(xyz, fps, out, nxyz);
    ballq_kernel<<<2048, 256, 0, stream>>>(xyz, nxyz, idx);
    conv1_kernel<<<1024, 256, 0, stream>>>(xyz, points, nxyz, idx, W0, b0, y1, p1);
    stats_kernel<<<1, 1024, 0, stream>>>(p1, 1024, 64, g0, be0, scl + 0, scl + 64);
    conv2_kernel<<<2048, 256, 0, stream>>>(y1, W1, b1, scl, y2, p2);
    stats_kernel<<<1, 1024, 0, stream>>>(p2, 2048, 64, g1, be1, scl + 128, scl + 192);
    conv3_kernel<<<2048, 256, 0, stream>>>(y2, W2, b2, scl, mx, mn, p3);
    stats_kernel<<<1, 1024, 0, stream>>>(p3, 2048, 128, g2, be2, scl + 256, scl + 384);
    final_kernel<<<4096, 256, 0, stream>>>(mx, mn, scl, out + 24576);
}